// Round 1
// baseline (530.942 us; speedup 1.0000x reference)
//
#include <hip/hip_runtime.h>
#include <hip/hip_bf16.h>

#define K_ORDER 10
#define NNODES  100000
#define NEDGES  3200000

typedef __bf16 bf16x8 __attribute__((ext_vector_type(8)));
typedef float  floatx4 __attribute__((ext_vector_type(4)));

struct WS {
  float* d;        // 11 monomial coefficients
  int*   jmax;     // highest nonzero coefficient index (0 => no adjacency passes)
  int*   cnt;      // N   degree counts
  int*   off;      // N+1 CSR offsets
  int*   cursor;   // N   scatter cursors
  float* dinv;     // N   deg^-1/2
  int*   csr_col;  // E
  float* csr_w;    // E
  short* h1;       // M x 256 bf16
  float* h2;       // M x 64 f32
  float* buf0;     // M x 64 f32 (Horner ping)
  float* buf1;     // M x 64 f32 (Horner pong)
};

__device__ inline short f2bf(float f) {
  __hip_bfloat16 h = __float2bfloat16(f);
  return __builtin_bit_cast(short, h);
}

__device__ inline void loadcvt4(const float* p, short* d) {
  float4 v = *(const float4*)p;
  d[0] = f2bf(v.x); d[1] = f2bf(v.y); d[2] = f2bf(v.z); d[3] = f2bf(v.w);
}
__device__ inline void loadcvt4(const short* p, short* d) {
  short4 v = *(const short4*)p;
  d[0] = v.x; d[1] = v.y; d[2] = v.z; d[3] = v.w;
}

// ---------------- coefficient kernel (1 block) ----------------
// p(A) = sum_k relu(temp_k)*C(10,k)/1024 * (I+A)^(10-k) (I-A)^k  ==  sum_j d_j A^j
__global__ void k_coeff(const float* __restrict__ temp, WS ws) {
  if (threadIdx.x != 0) return;
  const double C10[11] = {1,10,45,120,210,252,210,120,45,10,1};
  double dd[11];
  for (int j = 0; j <= K_ORDER; ++j) dd[j] = 0.0;
  for (int k = 0; k <= K_ORDER; ++k) {
    double th = temp[k] > 0.f ? (double)temp[k] : 0.0;
    double c  = th * C10[k] / 1024.0;
    double p[11];
    for (int j = 0; j <= K_ORDER; ++j) p[j] = 0.0;
    p[0] = 1.0;
    int deg = 0;
    for (int i = 0; i < K_ORDER - k; ++i) {   // * (1 + t)
      ++deg;
      for (int j = deg; j >= 1; --j) p[j] += p[j-1];
    }
    for (int i = 0; i < k; ++i) {             // * (1 - t)
      ++deg;
      for (int j = deg; j >= 1; --j) p[j] = p[j] - p[j-1];
    }
    for (int j = 0; j <= K_ORDER; ++j) dd[j] += c * p[j];
  }
  int jm = 0;
  for (int j = 1; j <= K_ORDER; ++j) if (dd[j] != 0.0) jm = j;
  for (int j = 0; j <= K_ORDER; ++j) ws.d[j] = (float)dd[j];
  *ws.jmax = jm;
}

// ---------------- GEMM: C = act(A @ B + bias) ----------------
// A: M x Kd (float or bf16-as-short, row major). B: Kd x Nd f32 row major.
// 64x64 tile / block (256 thr, 4 waves), BK=32, mfma_f32_16x16x32_bf16.
template<typename AT, bool RELU, bool BF16OUT>
__global__ __launch_bounds__(256) void k_gemm(const AT* __restrict__ A,
    const float* __restrict__ B, const float* __restrict__ bias,
    void* __restrict__ Cout, int M, int Kd, int Nd)
{
  __shared__ short As[64][40];   // [m][k], +8 pad breaks bank conflicts
  __shared__ short Bs[64][40];   // [n][k] (transposed)
  const int tid  = threadIdx.x;
  const int wave = tid >> 6, lane = tid & 63;
  const int m16  = lane & 15, q = lane >> 4;
  const int bm   = blockIdx.y * 64, bn = blockIdx.x * 64;

  const int rA  = tid >> 3, k0A = (tid & 7) << 2;   // A staging: 2 rows x 4 k
  const int kB  = tid >> 4, n0B = (tid & 15) << 2;  // B staging: 2 k x 4 n

  floatx4 acc[4] = {{0,0,0,0},{0,0,0,0},{0,0,0,0},{0,0,0,0}};

  for (int kt = 0; kt < Kd; kt += 32) {
    __syncthreads();
#pragma unroll
    for (int rr = 0; rr < 2; ++rr) {
      int row = bm + rA + rr * 32;
      if (row > M - 1) row = M - 1;   // clamp; stores are guarded
      short t4[4];
      loadcvt4(A + (size_t)row * Kd + kt + k0A, t4);
      *(short4*)&As[rA + rr * 32][k0A] = make_short4(t4[0], t4[1], t4[2], t4[3]);
    }
#pragma unroll
    for (int rr = 0; rr < 2; ++rr) {
      int k = kB + rr * 16;
      float4 v = *(const float4*)(B + (size_t)(kt + k) * Nd + bn + n0B);
      Bs[n0B + 0][k] = f2bf(v.x);
      Bs[n0B + 1][k] = f2bf(v.y);
      Bs[n0B + 2][k] = f2bf(v.z);
      Bs[n0B + 3][k] = f2bf(v.w);
    }
    __syncthreads();
    bf16x8 af = *(const bf16x8*)&As[wave * 16 + m16][q * 8];
#pragma unroll
    for (int c = 0; c < 4; ++c) {
      bf16x8 bf = *(const bf16x8*)&Bs[c * 16 + m16][q * 8];
      acc[c] = __builtin_amdgcn_mfma_f32_16x16x32_bf16(af, bf, acc[c], 0, 0, 0);
    }
  }

#pragma unroll
  for (int c = 0; c < 4; ++c) {
    int coln = bn + c * 16 + m16;
    float bv = bias[coln];
#pragma unroll
    for (int r = 0; r < 4; ++r) {
      int rowm = bm + wave * 16 + q * 4 + r;
      if (rowm < M) {
        float v = acc[c][r] + bv;
        if (RELU) v = fmaxf(v, 0.f);
        size_t o = (size_t)rowm * Nd + coln;
        if (BF16OUT) ((short*)Cout)[o] = f2bf(v);
        else         ((float*)Cout)[o] = v;
      }
    }
  }
}

// ---------------- gated graph-prep kernels ----------------
__global__ void k_zero(WS ws) {
  if (*ws.jmax == 0) return;
  int stride = gridDim.x * blockDim.x;
  for (int i = blockIdx.x * blockDim.x + threadIdx.x; i < NNODES; i += stride) {
    ws.cnt[i] = 0; ws.cursor[i] = 0;
  }
}

__global__ void k_count(const int* __restrict__ ei, WS ws) {
  if (*ws.jmax == 0) return;
  int stride = gridDim.x * blockDim.x;
  for (int e = blockIdx.x * blockDim.x + threadIdx.x; e < NEDGES; e += stride)
    atomicAdd(&ws.cnt[ei[e]], 1);
}

__global__ __launch_bounds__(1024) void k_scan(WS ws) {
  if (*ws.jmax == 0) return;
  __shared__ int sdata[1024];
  __shared__ int carry;
  const int t = threadIdx.x;
  if (t == 0) { carry = 0; ws.off[0] = 0; }
  __syncthreads();
  for (int base = 0; base < NNODES; base += 1024) {
    int i = base + t;
    int v = (i < NNODES) ? ws.cnt[i] : 0;
    if (i < NNODES) ws.dinv[i] = v > 0 ? rsqrtf((float)v) : 0.f;
    sdata[t] = v;
    __syncthreads();
    for (int o = 1; o < 1024; o <<= 1) {
      int add = (t >= o) ? sdata[t - o] : 0;
      __syncthreads();
      sdata[t] += add;
      __syncthreads();
    }
    if (i < NNODES) ws.off[i + 1] = carry + sdata[t];
    __syncthreads();
    if (t == 1023) carry += sdata[1023];
    __syncthreads();
  }
}

__global__ void k_scatter(const int* __restrict__ ei, WS ws) {
  if (*ws.jmax == 0) return;
  int stride = gridDim.x * blockDim.x;
  for (int e = blockIdx.x * blockDim.x + threadIdx.x; e < NEDGES; e += stride) {
    int row = ei[e], col = ei[NEDGES + e];
    float wv = ws.dinv[row] * ws.dinv[col];
    int pos = ws.off[row] + atomicAdd(&ws.cursor[row], 1);
    ws.csr_col[pos] = col;
    ws.csr_w[pos]   = wv;
  }
}

__global__ void k_init(WS ws) {
  int jm = *ws.jmax;
  if (jm == 0) return;
  float s = ws.d[jm];
  float* dst = (jm & 1) ? ws.buf1 : ws.buf0;
  int stride = gridDim.x * blockDim.x;
  for (int i = blockIdx.x * blockDim.x + threadIdx.x; i < NNODES * 64; i += stride)
    dst[i] = s * ws.h2[i];
}

// Horner step j: acc_out = A_hat @ acc_in + d_j * h2.   one wave per node.
__global__ __launch_bounds__(256) void k_adj(WS ws, int j) {
  int jm = *ws.jmax;
  if (j >= jm) return;
  const float* src = ((j + 1) & 1) ? ws.buf1 : ws.buf0;
  float*       dst = (j & 1)       ? ws.buf1 : ws.buf0;
  float dj = ws.d[j];
  int lane = threadIdx.x & 63;
  int wid = blockIdx.x * 4 + (threadIdx.x >> 6);
  int nwaves = gridDim.x * 4;
  for (int node = wid; node < NNODES; node += nwaves) {
    int s = ws.off[node], e = ws.off[node + 1];
    float acc = 0.f;
    for (int base = s; base < e; base += 64) {
      int idx = base + lane;
      int cc = 0; float cw = 0.f;
      if (idx < e) { cc = ws.csr_col[idx]; cw = ws.csr_w[idx]; }
      int n = min(64, e - base);
      for (int t = 0; t < n; ++t) {
        int   c2 = __shfl(cc, t);
        float w2 = __shfl(cw, t);
        acc += w2 * src[(size_t)c2 * 64 + lane];
      }
    }
    dst[(size_t)node * 64 + lane] = acc + dj * ws.h2[(size_t)node * 64 + lane];
  }
}

// ---------------- log_softmax (one wave per row of 64) ----------------
__global__ __launch_bounds__(256) void k_lsm(WS ws, float* __restrict__ out) {
  int wid = blockIdx.x * 4 + (threadIdx.x >> 6);
  if (wid >= NNODES) return;
  int lane = threadIdx.x & 63;
  size_t idx = (size_t)wid * 64 + lane;
  int jm = *ws.jmax;
  float v = (jm == 0) ? ws.d[0] * ws.h2[idx] : ws.buf0[idx];
  float m = v;
#pragma unroll
  for (int o = 32; o > 0; o >>= 1) m = fmaxf(m, __shfl_xor(m, o));
  float s = __expf(v - m);
#pragma unroll
  for (int o = 32; o > 0; o >>= 1) s += __shfl_xor(s, o);
  out[idx] = (v - m) - __logf(s);
}

// ---------------- host ----------------
extern "C" void kernel_launch(void* const* d_in, const int* in_sizes, int n_in,
                              void* d_out, int out_size, void* d_ws, size_t ws_size,
                              hipStream_t stream) {
  const float* x    = (const float*)d_in[0];
  const int*   ei   = (const int*)  d_in[1];
  const float* W1   = (const float*)d_in[2];
  const float* b1   = (const float*)d_in[3];
  const float* W2   = (const float*)d_in[4];
  const float* b2   = (const float*)d_in[5];
  const float* temp = (const float*)d_in[6];
  float* out = (float*)d_out;

  char* w = (char*)d_ws;
  size_t o = 0;
  auto bump = [&](size_t bytes) { size_t r = o; o += (bytes + 255) & ~(size_t)255; return r; };
  WS ws;
  ws.d       = (float*)(w + bump(11 * 4));
  ws.jmax    = (int*)  (w + bump(4));
  ws.cnt     = (int*)  (w + bump((size_t)NNODES * 4));
  ws.off     = (int*)  (w + bump((size_t)(NNODES + 1) * 4));
  ws.cursor  = (int*)  (w + bump((size_t)NNODES * 4));
  ws.dinv    = (float*)(w + bump((size_t)NNODES * 4));
  ws.csr_col = (int*)  (w + bump((size_t)NEDGES * 4));
  ws.csr_w   = (float*)(w + bump((size_t)NEDGES * 4));
  ws.h1      = (short*)(w + bump((size_t)NNODES * 256 * 2));
  ws.h2      = (float*)(w + bump((size_t)NNODES * 64 * 4));
  ws.buf0    = (float*)(w + bump((size_t)NNODES * 64 * 4));
  ws.buf1    = (float*)(w + bump((size_t)NNODES * 64 * 4));

  const int MBLK = (NNODES + 63) / 64;  // 1563

  k_coeff<<<1, 64, 0, stream>>>(temp, ws);
  // h1 = relu(x @ W1 + b1)  -> bf16
  k_gemm<float, true,  true ><<<dim3(4, MBLK), 256, 0, stream>>>(x, W1, b1, ws.h1, NNODES, 512, 256);
  // h2 = h1 @ W2 + b2       -> f32
  k_gemm<short, false, false><<<dim3(1, MBLK), 256, 0, stream>>>(ws.h1, W2, b2, ws.h2, NNODES, 256, 64);
  // gated propagation path (no-op when jmax==0, i.e. temp==ones)
  k_zero   <<<512,  256, 0, stream>>>(ws);
  k_count  <<<1024, 256, 0, stream>>>(ei, ws);
  k_scan   <<<1,   1024, 0, stream>>>(ws);
  k_scatter<<<1024, 256, 0, stream>>>(ei, ws);
  k_init   <<<1024, 256, 0, stream>>>(ws);
  for (int j = K_ORDER - 1; j >= 0; --j)
    k_adj<<<1024, 256, 0, stream>>>(ws, j);
  k_lsm<<<25000, 256, 0, stream>>>(ws, out);
}

// Round 2
// 416.405 us; speedup vs baseline: 1.2751x; 1.2751x over previous
//
#include <hip/hip_runtime.h>
#include <hip/hip_bf16.h>

#define K_ORDER 10
#define NNODES  100000
#define NEDGES  3200000

typedef __bf16 bf16x8 __attribute__((ext_vector_type(8)));
typedef float  floatx4 __attribute__((ext_vector_type(4)));

struct WS {
  float* d;        // 11 monomial coefficients
  int*   jmax;     // highest nonzero coefficient index (0 => no adjacency passes)
  int*   cnt;      // N   degree counts
  int*   off;      // N+1 CSR offsets
  int*   cursor;   // N   scatter cursors
  float* dinv;     // N   deg^-1/2
  int*   csr_col;  // E
  float* csr_w;    // E
  short* h1;       // M x 256 bf16
  float* h2;       // M x 64 f32
  float* buf0;     // M x 64 f32 (Horner ping)
  float* buf1;     // M x 64 f32 (Horner pong)
  short* w1s;      // W1 bf16 in MFMA-fragment order
  short* w2s;      // W2 bf16 in MFMA-fragment order
};

__device__ inline short f2bf(float f) {
  __hip_bfloat16 h = __float2bfloat16(f);
  return __builtin_bit_cast(short, h);
}

// ---------------- coefficient kernel (1 block) ----------------
// p(A) = sum_k relu(temp_k)*C(10,k)/1024 * (I+A)^(10-k) (I-A)^k  ==  sum_j d_j A^j
__global__ void k_coeff(const float* __restrict__ temp, WS ws) {
  if (threadIdx.x != 0) return;
  const double C10[11] = {1,10,45,120,210,252,210,120,45,10,1};
  double dd[11];
  for (int j = 0; j <= K_ORDER; ++j) dd[j] = 0.0;
  for (int k = 0; k <= K_ORDER; ++k) {
    double th = temp[k] > 0.f ? (double)temp[k] : 0.0;
    double c  = th * C10[k] / 1024.0;
    double p[11];
    for (int j = 0; j <= K_ORDER; ++j) p[j] = 0.0;
    p[0] = 1.0;
    int deg = 0;
    for (int i = 0; i < K_ORDER - k; ++i) {   // * (1 + t)
      ++deg;
      for (int j = deg; j >= 1; --j) p[j] += p[j-1];
    }
    for (int i = 0; i < k; ++i) {             // * (1 - t)
      ++deg;
      for (int j = deg; j >= 1; --j) p[j] = p[j] - p[j-1];
    }
    for (int j = 0; j <= K_ORDER; ++j) dd[j] += c * p[j];
  }
  int jm = 0;
  for (int j = 1; j <= K_ORDER; ++j) if (dd[j] != 0.0) jm = j;
  for (int j = 0; j <= K_ORDER; ++j) ws.d[j] = (float)dd[j];
  *ws.jmax = jm;
}

// ---------------- weight pre-swizzle: f32 row-major -> bf16 fragment order ----
// dst frag (kt, nc), lane l=q*16+m16 holds W[kt*32+q*8+j][nc*16+m16], j=0..7.
// dst[((kt*(Nd/16)+nc)*64 + l)*8 + j]
__global__ void k_swz(const float* __restrict__ W, short* __restrict__ dst,
                      int Kd, int Nd) {
  int t = blockIdx.x * blockDim.x + threadIdx.x;
  int total = (Kd >> 5) * (Nd >> 4) * 64;
  if (t >= total) return;
  int lane = t & 63, frag = t >> 6;
  int nfr = Nd >> 4;
  int kt = frag / nfr, nc = frag - kt * nfr;
  int m16 = lane & 15, q = lane >> 4;
  int kbase = kt * 32 + q * 8;
  int col = nc * 16 + m16;
  short v[8];
#pragma unroll
  for (int j = 0; j < 8; ++j) v[j] = f2bf(W[(size_t)(kbase + j) * Nd + col]);
  short4* o = (short4*)&dst[(size_t)t * 8];
  o[0] = make_short4(v[0], v[1], v[2], v[3]);
  o[1] = make_short4(v[4], v[5], v[6], v[7]);
}

// ---------------- GEMM1: h1 = relu(x @ W1 + b1), bf16 out ----------------
// One block per 64-row slab; wave w owns cols w*64..w*64+63. K=512, BK=32.
// A staged in LDS in fragment order; B frags direct from pre-swizzled global.
__global__ __launch_bounds__(256) void k_gemm1(const float* __restrict__ A,
    const short* __restrict__ Bsw, const float* __restrict__ bias,
    short* __restrict__ H1)
{
  __shared__ short As[4 * 64 * 8];   // [r][lane][8] fragment order, 4 KB
  const int tid = threadIdx.x;
  const int wave = tid >> 6, lane = tid & 63;
  const int q = lane >> 4, m16 = lane & 15;
  const int bm = blockIdx.x * 64;

  // staging role: row = tid>>2 (0..63), kq = tid&3 (8 k each)
  const int srow = tid >> 2, kq = tid & 3;
  const int r_ = srow >> 4, m_ = srow & 15;
  int grow = bm + srow; if (grow > NNODES - 1) grow = NNODES - 1;
  const float* aptr = A + (size_t)grow * 512 + kq * 8;
  short* sdst = &As[r_ * 512 + (kq * 16 + m_) * 8];

  float4 p0 = *(const float4*)(aptr);
  float4 p1 = *(const float4*)(aptr + 4);

  floatx4 acc[4][4] = {};

#pragma unroll 1
  for (int kt = 0; kt < 16; ++kt) {
    __syncthreads();
    ((short4*)sdst)[0] = make_short4(f2bf(p0.x), f2bf(p0.y), f2bf(p0.z), f2bf(p0.w));
    ((short4*)sdst)[1] = make_short4(f2bf(p1.x), f2bf(p1.y), f2bf(p1.z), f2bf(p1.w));
    __syncthreads();
    if (kt < 15) {
      p0 = *(const float4*)(aptr + (kt + 1) * 32);
      p1 = *(const float4*)(aptr + (kt + 1) * 32 + 4);
    }
    const short* bbase = Bsw + ((size_t)(kt * 16 + wave * 4) * 64 + lane) * 8;
    bf16x8 bf[4];
#pragma unroll
    for (int c = 0; c < 4; ++c) bf[c] = *(const bf16x8*)(bbase + c * 512);
    bf16x8 af[4];
#pragma unroll
    for (int r = 0; r < 4; ++r) af[r] = *(const bf16x8*)&As[r * 512 + lane * 8];
#pragma unroll
    for (int r = 0; r < 4; ++r)
#pragma unroll
      for (int c = 0; c < 4; ++c)
        acc[r][c] = __builtin_amdgcn_mfma_f32_16x16x32_bf16(af[r], bf[c], acc[r][c], 0, 0, 0);
  }

  // epilogue: row = bm + r*16 + q*4 + reg, col = wave*64 + c*16 + m16
  float bv[4];
#pragma unroll
  for (int c = 0; c < 4; ++c) bv[c] = bias[wave * 64 + c * 16 + m16];
#pragma unroll
  for (int r = 0; r < 4; ++r) {
    int rb = bm + r * 16 + q * 4;
#pragma unroll
    for (int reg = 0; reg < 4; ++reg) {
      int rowm = rb + reg;
      if (rowm < NNODES) {
        size_t o = (size_t)rowm * 256 + wave * 64 + m16;
#pragma unroll
        for (int c = 0; c < 4; ++c)
          H1[o + c * 16] = f2bf(fmaxf(acc[r][c][reg] + bv[c], 0.f));
      }
    }
  }
}

// ---------------- GEMM2 + bias (+ fused log_softmax when jmax==0) ------------
// One block per 64-row slab; wave w owns rows w*16..w*16+15, all 64 cols.
// A frags direct from global h1 (coalesces to 64 B/row segments); B frags from
// pre-swizzled W2 (32 KB, cache-resident). No LDS, no barriers.
__global__ __launch_bounds__(256) void k_gemm2(const short* __restrict__ H1,
    const short* __restrict__ B2sw, const float* __restrict__ bias,
    WS ws, float* __restrict__ out)
{
  const int tid = threadIdx.x;
  const int wave = tid >> 6, lane = tid & 63;
  const int q = lane >> 4, m16 = lane & 15;
  const int bm = blockIdx.x * 64;
  int grow = bm + wave * 16 + m16; if (grow > NNODES - 1) grow = NNODES - 1;
  const short* arow = H1 + (size_t)grow * 256 + q * 8;

  floatx4 acc[4] = {};
#pragma unroll
  for (int kt = 0; kt < 8; ++kt) {
    bf16x8 af = *(const bf16x8*)(arow + kt * 32);
    const short* bbase = B2sw + ((size_t)(kt * 4) * 64 + lane) * 8;
#pragma unroll
    for (int c = 0; c < 4; ++c) {
      bf16x8 bf = *(const bf16x8*)(bbase + c * 512);
      acc[c] = __builtin_amdgcn_mfma_f32_16x16x32_bf16(af, bf, acc[c], 0, 0, 0);
    }
  }

  int jm = *ws.jmax;
  float d0 = ws.d[0];
  float bv[4];
#pragma unroll
  for (int c = 0; c < 4; ++c) bv[c] = bias[c * 16 + m16];

  if (jm > 0) {
    // store h2 for the general propagation path
#pragma unroll
    for (int reg = 0; reg < 4; ++reg) {
      int rowm = bm + wave * 16 + q * 4 + reg;
      if (rowm < NNODES) {
        size_t o = (size_t)rowm * 64 + m16;
#pragma unroll
        for (int c = 0; c < 4; ++c)
          ws.h2[o + c * 16] = acc[c][reg] + bv[c];
      }
    }
  } else {
    // out = log_softmax(d0 * h2) directly
#pragma unroll
    for (int reg = 0; reg < 4; ++reg) {
      float v[4];
#pragma unroll
      for (int c = 0; c < 4; ++c) v[c] = d0 * (acc[c][reg] + bv[c]);
      float m = fmaxf(fmaxf(v[0], v[1]), fmaxf(v[2], v[3]));
#pragma unroll
      for (int o = 1; o < 16; o <<= 1) m = fmaxf(m, __shfl_xor(m, o));
      float s = 0.f;
#pragma unroll
      for (int c = 0; c < 4; ++c) s += __expf(v[c] - m);
#pragma unroll
      for (int o = 1; o < 16; o <<= 1) s += __shfl_xor(s, o);
      float ls = __logf(s);
      int rowm = bm + wave * 16 + q * 4 + reg;
      if (rowm < NNODES) {
        size_t o = (size_t)rowm * 64 + m16;
#pragma unroll
        for (int c = 0; c < 4; ++c) out[o + c * 16] = v[c] - m - ls;
      }
    }
  }
}

// ---------------- gated graph-prep kernels ----------------
__global__ void k_zero(WS ws) {
  if (*ws.jmax == 0) return;
  int stride = gridDim.x * blockDim.x;
  for (int i = blockIdx.x * blockDim.x + threadIdx.x; i < NNODES; i += stride) {
    ws.cnt[i] = 0; ws.cursor[i] = 0;
  }
}

__global__ void k_count(const int* __restrict__ ei, WS ws) {
  if (*ws.jmax == 0) return;
  int stride = gridDim.x * blockDim.x;
  for (int e = blockIdx.x * blockDim.x + threadIdx.x; e < NEDGES; e += stride)
    atomicAdd(&ws.cnt[ei[e]], 1);
}

__global__ __launch_bounds__(1024) void k_scan(WS ws) {
  if (*ws.jmax == 0) return;
  __shared__ int sdata[1024];
  __shared__ int carry;
  const int t = threadIdx.x;
  if (t == 0) { carry = 0; ws.off[0] = 0; }
  __syncthreads();
  for (int base = 0; base < NNODES; base += 1024) {
    int i = base + t;
    int v = (i < NNODES) ? ws.cnt[i] : 0;
    if (i < NNODES) ws.dinv[i] = v > 0 ? rsqrtf((float)v) : 0.f;
    sdata[t] = v;
    __syncthreads();
    for (int o = 1; o < 1024; o <<= 1) {
      int add = (t >= o) ? sdata[t - o] : 0;
      __syncthreads();
      sdata[t] += add;
      __syncthreads();
    }
    if (i < NNODES) ws.off[i + 1] = carry + sdata[t];
    __syncthreads();
    if (t == 1023) carry += sdata[1023];
    __syncthreads();
  }
}

__global__ void k_scatter(const int* __restrict__ ei, WS ws) {
  if (*ws.jmax == 0) return;
  int stride = gridDim.x * blockDim.x;
  for (int e = blockIdx.x * blockDim.x + threadIdx.x; e < NEDGES; e += stride) {
    int row = ei[e], col = ei[NEDGES + e];
    float wv = ws.dinv[row] * ws.dinv[col];
    int pos = ws.off[row] + atomicAdd(&ws.cursor[row], 1);
    ws.csr_col[pos] = col;
    ws.csr_w[pos]   = wv;
  }
}

__global__ void k_init(WS ws) {
  int jm = *ws.jmax;
  if (jm == 0) return;
  float s = ws.d[jm];
  float* dst = (jm & 1) ? ws.buf1 : ws.buf0;
  int stride = gridDim.x * blockDim.x;
  for (int i = blockIdx.x * blockDim.x + threadIdx.x; i < NNODES * 64; i += stride)
    dst[i] = s * ws.h2[i];
}

// Horner step j: acc_out = A_hat @ acc_in + d_j * h2.   one wave per node.
__global__ __launch_bounds__(256) void k_adj(WS ws, int j) {
  int jm = *ws.jmax;
  if (j >= jm) return;
  const float* src = ((j + 1) & 1) ? ws.buf1 : ws.buf0;
  float*       dst = (j & 1)       ? ws.buf1 : ws.buf0;
  float dj = ws.d[j];
  int lane = threadIdx.x & 63;
  int wid = blockIdx.x * 4 + (threadIdx.x >> 6);
  int nwaves = gridDim.x * 4;
  for (int node = wid; node < NNODES; node += nwaves) {
    int s = ws.off[node], e = ws.off[node + 1];
    float acc = 0.f;
    for (int base = s; base < e; base += 64) {
      int idx = base + lane;
      int cc = 0; float cw = 0.f;
      if (idx < e) { cc = ws.csr_col[idx]; cw = ws.csr_w[idx]; }
      int n = min(64, e - base);
      for (int t = 0; t < n; ++t) {
        int   c2 = __shfl(cc, t);
        float w2 = __shfl(cw, t);
        acc += w2 * src[(size_t)c2 * 64 + lane];
      }
    }
    dst[(size_t)node * 64 + lane] = acc + dj * ws.h2[(size_t)node * 64 + lane];
  }
}

// ---------------- log_softmax for the general path (jmax>0 only) -------------
__global__ __launch_bounds__(256) void k_lsm(WS ws, float* __restrict__ out) {
  if (*ws.jmax == 0) return;
  int wid = blockIdx.x * 4 + (threadIdx.x >> 6);
  if (wid >= NNODES) return;
  int lane = threadIdx.x & 63;
  size_t idx = (size_t)wid * 64 + lane;
  float v = ws.buf0[idx];
  float m = v;
#pragma unroll
  for (int o = 32; o > 0; o >>= 1) m = fmaxf(m, __shfl_xor(m, o));
  float s = __expf(v - m);
#pragma unroll
  for (int o = 32; o > 0; o >>= 1) s += __shfl_xor(s, o);
  out[idx] = (v - m) - __logf(s);
}

// ---------------- host ----------------
extern "C" void kernel_launch(void* const* d_in, const int* in_sizes, int n_in,
                              void* d_out, int out_size, void* d_ws, size_t ws_size,
                              hipStream_t stream) {
  const float* x    = (const float*)d_in[0];
  const int*   ei   = (const int*)  d_in[1];
  const float* W1   = (const float*)d_in[2];
  const float* b1   = (const float*)d_in[3];
  const float* W2   = (const float*)d_in[4];
  const float* b2   = (const float*)d_in[5];
  const float* temp = (const float*)d_in[6];
  float* out = (float*)d_out;

  char* w = (char*)d_ws;
  size_t o = 0;
  auto bump = [&](size_t bytes) { size_t r = o; o += (bytes + 255) & ~(size_t)255; return r; };
  WS ws;
  ws.d       = (float*)(w + bump(11 * 4));
  ws.jmax    = (int*)  (w + bump(4));
  ws.cnt     = (int*)  (w + bump((size_t)NNODES * 4));
  ws.off     = (int*)  (w + bump((size_t)(NNODES + 1) * 4));
  ws.cursor  = (int*)  (w + bump((size_t)NNODES * 4));
  ws.dinv    = (float*)(w + bump((size_t)NNODES * 4));
  ws.csr_col = (int*)  (w + bump((size_t)NEDGES * 4));
  ws.csr_w   = (float*)(w + bump((size_t)NEDGES * 4));
  ws.h1      = (short*)(w + bump((size_t)NNODES * 256 * 2));
  ws.h2      = (float*)(w + bump((size_t)NNODES * 64 * 4));
  ws.buf0    = (float*)(w + bump((size_t)NNODES * 64 * 4));
  ws.buf1    = (float*)(w + bump((size_t)NNODES * 64 * 4));
  ws.w1s     = (short*)(w + bump((size_t)512 * 256 * 2));
  ws.w2s     = (short*)(w + bump((size_t)256 * 64 * 2));

  const int MBLK = (NNODES + 63) / 64;  // 1563

  k_coeff<<<1, 64, 0, stream>>>(temp, ws);
  k_swz<<<64, 256, 0, stream>>>(W1, ws.w1s, 512, 256);
  k_swz<<<8, 256, 0, stream>>>(W2, ws.w2s, 256, 64);
  k_gemm1<<<MBLK, 256, 0, stream>>>(x, ws.w1s, b1, ws.h1);
  k_gemm2<<<MBLK, 256, 0, stream>>>(ws.h1, ws.w2s, b2, ws, out);
  // gated propagation path (no-op when jmax==0, i.e. temp==ones)
  k_zero   <<<512,  256, 0, stream>>>(ws);
  k_count  <<<1024, 256, 0, stream>>>(ei, ws);
  k_scan   <<<1,   1024, 0, stream>>>(ws);
  k_scatter<<<1024, 256, 0, stream>>>(ei, ws);
  k_init   <<<1024, 256, 0, stream>>>(ws);
  for (int j = K_ORDER - 1; j >= 0; --j)
    k_adj<<<1024, 256, 0, stream>>>(ws, j);
  k_lsm<<<25000, 256, 0, stream>>>(ws, out);
}

// Round 3
// 391.294 us; speedup vs baseline: 1.3569x; 1.0642x over previous
//
#include <hip/hip_runtime.h>
#include <hip/hip_bf16.h>
#include <hip/hip_cooperative_groups.h>

namespace cg = cooperative_groups;

#define K_ORDER 10
#define NNODES  100000
#define NEDGES  3200000

typedef __bf16 bf16x8 __attribute__((ext_vector_type(8)));
typedef float  floatx4 __attribute__((ext_vector_type(4)));

struct WS {
  float* d;        // 11 monomial coefficients
  int*   jmax;     // highest nonzero coefficient index (0 => identity propagation)
  int*   cnt;      // N   degree counts
  int*   off;      // N+1 CSR offsets
  int*   cursor;   // N   scatter cursors
  float* dinv;     // N   deg^-1/2
  int*   csr_col;  // E
  float* csr_w;    // E
  float* h2;       // M x 64 f32 (pre-propagation logits, general path only)
  float* buf0;     // M x 64 f32 (Horner ping)
  float* buf1;     // M x 64 f32 (Horner pong)
  short* w1s;      // W1 bf16 in MFMA-fragment order
  short* w2s;      // W2 bf16 in MFMA-fragment order
  int*   bsum;     // 512 block sums (scan)
  int*   bbase;    // 512 block bases (scan)
};

__device__ inline short f2bf(float f) {
  __hip_bfloat16 h = __float2bfloat16(f);
  return __builtin_bit_cast(short, h);
}

// ---- weight swizzle body: f32 row-major -> bf16 MFMA B-fragment order ----
// frag (kt, nc): lane l = q*16+m16 holds W[kt*32+q*8+j][nc*16+m16], j=0..7.
__device__ inline void swz_body(const float* __restrict__ W, short* __restrict__ dst,
                                int Kd, int Nd, int t) {
  int lane = t & 63, frag = t >> 6;
  int nfr = Nd >> 4;
  int kt = frag / nfr, nc = frag - kt * nfr;
  int m16 = lane & 15, q = lane >> 4;
  int kbase = kt * 32 + q * 8;
  int col = nc * 16 + m16;
  short v[8];
#pragma unroll
  for (int j = 0; j < 8; ++j) v[j] = f2bf(W[(size_t)(kbase + j) * Nd + col]);
  short4* o = (short4*)&dst[(size_t)t * 8];
  o[0] = make_short4(v[0], v[1], v[2], v[3]);
  o[1] = make_short4(v[4], v[5], v[6], v[7]);
}

// ---- combined: W1 swizzle (blocks 0..63), W2 swizzle (64..71), coeff (72) ----
__global__ __launch_bounds__(256) void k_swzall(const float* __restrict__ W1,
    const float* __restrict__ W2, const float* __restrict__ temp, WS ws) {
  int b = blockIdx.x;
  if (b < 64) {
    swz_body(W1, ws.w1s, 512, 256, b * 256 + threadIdx.x);
  } else if (b < 72) {
    swz_body(W2, ws.w2s, 256, 64, (b - 64) * 256 + threadIdx.x);
  } else if (threadIdx.x == 0) {
    // p(A) = sum_k relu(temp_k)*C(10,k)/1024 * (I+A)^(10-k)(I-A)^k = sum_j d_j A^j
    const double C10[11] = {1,10,45,120,210,252,210,120,45,10,1};
    double dd[11];
    for (int j = 0; j <= K_ORDER; ++j) dd[j] = 0.0;
    for (int k = 0; k <= K_ORDER; ++k) {
      double th = temp[k] > 0.f ? (double)temp[k] : 0.0;
      double c  = th * C10[k] / 1024.0;
      double p[11];
      for (int j = 0; j <= K_ORDER; ++j) p[j] = 0.0;
      p[0] = 1.0;
      int deg = 0;
      for (int i = 0; i < K_ORDER - k; ++i) {   // * (1 + t)
        ++deg;
        for (int j = deg; j >= 1; --j) p[j] += p[j-1];
      }
      for (int i = 0; i < k; ++i) {             // * (1 - t)
        ++deg;
        for (int j = deg; j >= 1; --j) p[j] = p[j] - p[j-1];
      }
      for (int j = 0; j <= K_ORDER; ++j) dd[j] += c * p[j];
    }
    int jm = 0;
    for (int j = 1; j <= K_ORDER; ++j) if (dd[j] != 0.0) jm = j;
    for (int j = 0; j <= K_ORDER; ++j) ws.d[j] = (float)dd[j];
    *ws.jmax = jm;
  }
}

// ---- fused forward: relu(x@W1+b1)@W2+b2, then (jmax==0) log_softmax -> out
//                      else h2 -> ws.h2 for the propagation path.
// One block per 64-row slab. Phase A: 64x256 GEMM1, wave w owns cols w*64..+63.
// Phase B: relu tile -> LDS (bf16, row-major +8 pad). Phase C: GEMM2 64x64,
// wave w owns rows w*16..+15. Phase D: epilogue.
__global__ __launch_bounds__(256) void k_fwd(const float* __restrict__ A,
    const float* __restrict__ b1, const float* __restrict__ b2,
    WS ws, float* __restrict__ out)
{
  __shared__ short As[4 * 64 * 8];     // GEMM1 A staging, fragment order, 4 KB
  __shared__ short H1s[64 * 264];      // h1 tile, row-major, +8 pad, 33 KB
  const int tid = threadIdx.x;
  const int wave = tid >> 6, lane = tid & 63;
  const int q = lane >> 4, m16 = lane & 15;
  const int bm = blockIdx.x * 64;

  // A staging role: row = tid>>2 (0..63), kq = tid&3 (8 k each)
  const int srow = tid >> 2, kq = tid & 3;
  const int r_ = srow >> 4, m_ = srow & 15;
  int grow = bm + srow; if (grow > NNODES - 1) grow = NNODES - 1;
  const float* aptr = A + (size_t)grow * 512 + kq * 8;
  short* sdst = &As[r_ * 512 + (kq * 16 + m_) * 8];

  float4 p0 = *(const float4*)(aptr);
  float4 p1 = *(const float4*)(aptr + 4);

  floatx4 acc[4][4] = {};

#pragma unroll 1
  for (int kt = 0; kt < 16; ++kt) {
    __syncthreads();
    ((short4*)sdst)[0] = make_short4(f2bf(p0.x), f2bf(p0.y), f2bf(p0.z), f2bf(p0.w));
    ((short4*)sdst)[1] = make_short4(f2bf(p1.x), f2bf(p1.y), f2bf(p1.z), f2bf(p1.w));
    __syncthreads();
    if (kt < 15) {
      p0 = *(const float4*)(aptr + (kt + 1) * 32);
      p1 = *(const float4*)(aptr + (kt + 1) * 32 + 4);
    }
    const short* bbase = ws.w1s + ((size_t)(kt * 16 + wave * 4) * 64 + lane) * 8;
    bf16x8 bf[4];
#pragma unroll
    for (int c = 0; c < 4; ++c) bf[c] = *(const bf16x8*)(bbase + c * 512);
    bf16x8 af[4];
#pragma unroll
    for (int r = 0; r < 4; ++r) af[r] = *(const bf16x8*)&As[r * 512 + lane * 8];
#pragma unroll
    for (int r = 0; r < 4; ++r)
#pragma unroll
      for (int c = 0; c < 4; ++c)
        acc[r][c] = __builtin_amdgcn_mfma_f32_16x16x32_bf16(af[r], bf[c], acc[r][c], 0, 0, 0);
  }

  // Phase B: bias + relu -> H1s bf16 tile (C-layout scatter, one-time)
  float bv[4];
#pragma unroll
  for (int c = 0; c < 4; ++c) bv[c] = b1[wave * 64 + c * 16 + m16];
  __syncthreads();   // As no longer needed; ensure all MFMAs read it (loop ended with reads)
#pragma unroll
  for (int r = 0; r < 4; ++r)
#pragma unroll
    for (int c = 0; c < 4; ++c)
#pragma unroll
      for (int reg = 0; reg < 4; ++reg)
        H1s[(r * 16 + q * 4 + reg) * 264 + wave * 64 + c * 16 + m16] =
            f2bf(fmaxf(acc[r][c][reg] + bv[c], 0.f));
  __syncthreads();

  // Phase C: GEMM2 — wave w computes rows w*16..+15, all 64 cols. K=256.
  floatx4 acc2[4] = {};
#pragma unroll
  for (int kt = 0; kt < 8; ++kt) {
    bf16x8 af2 = *(const bf16x8*)&H1s[(wave * 16 + m16) * 264 + kt * 32 + q * 8];
    const short* bb = ws.w2s + ((size_t)(kt * 4) * 64 + lane) * 8;
#pragma unroll
    for (int c = 0; c < 4; ++c) {
      bf16x8 bf2 = *(const bf16x8*)(bb + c * 512);
      acc2[c] = __builtin_amdgcn_mfma_f32_16x16x32_bf16(af2, bf2, acc2[c], 0, 0, 0);
    }
  }

  // Phase D: epilogue. row = bm + wave*16 + q*4 + reg, col = c*16 + m16.
  int jm = *ws.jmax;
  float d0 = ws.d[0];
  float bv2[4];
#pragma unroll
  for (int c = 0; c < 4; ++c) bv2[c] = b2[c * 16 + m16];

  if (jm > 0) {
#pragma unroll
    for (int reg = 0; reg < 4; ++reg) {
      int rowm = bm + wave * 16 + q * 4 + reg;
      if (rowm < NNODES) {
        size_t o = (size_t)rowm * 64 + m16;
#pragma unroll
        for (int c = 0; c < 4; ++c)
          ws.h2[o + c * 16] = acc2[c][reg] + bv2[c];
      }
    }
  } else {
#pragma unroll
    for (int reg = 0; reg < 4; ++reg) {
      float v[4];
#pragma unroll
      for (int c = 0; c < 4; ++c) v[c] = d0 * (acc2[c][reg] + bv2[c]);
      float m = fmaxf(fmaxf(v[0], v[1]), fmaxf(v[2], v[3]));
#pragma unroll
      for (int o = 1; o < 16; o <<= 1) m = fmaxf(m, __shfl_xor(m, o));
      float s = 0.f;
#pragma unroll
      for (int c = 0; c < 4; ++c) s += __expf(v[c] - m);
#pragma unroll
      for (int o = 1; o < 16; o <<= 1) s += __shfl_xor(s, o);
      float ls = __logf(s);
      int rowm = bm + wave * 16 + q * 4 + reg;
      if (rowm < NNODES) {
        size_t o = (size_t)rowm * 64 + m16;
#pragma unroll
        for (int c = 0; c < 4; ++c) out[o + c * 16] = v[c] - m - ls;
      }
    }
  }
}

// ---- cooperative graph-propagation path (entirely gated on jmax>0) ----
// 512 blocks x 256 threads. Phases: init/zero -> count -> scan -> scatter ->
// Horner adjacency passes -> log_softmax, with grid.sync() between phases.
__global__ __launch_bounds__(256) void k_graph(const int* __restrict__ ei,
                                               WS ws, float* __restrict__ out) {
  const int jm = *ws.jmax;
  if (jm == 0) return;   // uniform across grid: no sync executed by anyone
  cg::grid_group g = cg::this_grid();
  const int t = threadIdx.x;
  const int gtid = blockIdx.x * 256 + t;
  const int gstride = 512 * 256;

  // phase 1: zero cnt/cursor; init Horner buffer = d[jm] * h2
  for (int i = gtid; i < NNODES; i += gstride) { ws.cnt[i] = 0; ws.cursor[i] = 0; }
  {
    float s = ws.d[jm];
    float* dst = (jm & 1) ? ws.buf1 : ws.buf0;
    for (int i = gtid; i < NNODES * 64; i += gstride) dst[i] = s * ws.h2[i];
  }
  g.sync();

  // phase 2: degree count
  for (int e = gtid; e < NEDGES; e += gstride) atomicAdd(&ws.cnt[ei[e]], 1);
  g.sync();

  // phase 3: per-block inclusive scan of a 256-node chunk
  __shared__ int sd[256];
  const int i3 = blockIdx.x * 256 + t;
  {
    int v = (i3 < NNODES) ? ws.cnt[i3] : 0;
    if (i3 < NNODES) ws.dinv[i3] = v > 0 ? rsqrtf((float)v) : 0.f;
    sd[t] = v;
    __syncthreads();
    for (int o = 1; o < 256; o <<= 1) {
      int a = (t >= o) ? sd[t - o] : 0;
      __syncthreads();
      sd[t] += a;
      __syncthreads();
    }
    if (i3 < NNODES) ws.off[i3 + 1] = sd[t];
    if (t == 255) ws.bsum[blockIdx.x] = sd[255];
    if (blockIdx.x == 0 && t == 0) ws.off[0] = 0;
  }
  g.sync();

  // phase 4: block 0 exclusive-scans the 512 block sums
  if (blockIdx.x == 0) {
    __shared__ int sd2[512];
    sd2[t] = ws.bsum[t]; sd2[t + 256] = ws.bsum[t + 256];
    __syncthreads();
    if (t == 0) {
      int run = 0;
      for (int b = 0; b < 512; ++b) { int x = sd2[b]; sd2[b] = run; run += x; }
    }
    __syncthreads();
    ws.bbase[t] = sd2[t]; ws.bbase[t + 256] = sd2[t + 256];
  }
  g.sync();

  // phase 5: add block bases
  if (i3 < NNODES) ws.off[i3 + 1] += ws.bbase[blockIdx.x];
  g.sync();

  // phase 6: scatter edges into CSR
  for (int e = gtid; e < NEDGES; e += gstride) {
    int row = ei[e], col = ei[NEDGES + e];
    float wv = ws.dinv[row] * ws.dinv[col];
    int pos = ws.off[row] + atomicAdd(&ws.cursor[row], 1);
    ws.csr_col[pos] = col;
    ws.csr_w[pos]   = wv;
  }
  g.sync();

  // phase 7: Horner adjacency passes: dst = A_hat @ src + d_j * h2
  const int lane = t & 63;
  const int wid0 = blockIdx.x * 4 + (t >> 6);
  const int nwaves = 512 * 4;
  for (int j = jm - 1; j >= 0; --j) {
    const float* src = ((j + 1) & 1) ? ws.buf1 : ws.buf0;
    float*       dst = (j & 1)       ? ws.buf1 : ws.buf0;
    float dj = ws.d[j];
    for (int node = wid0; node < NNODES; node += nwaves) {
      int s = ws.off[node], e = ws.off[node + 1];
      float acc = 0.f;
      for (int base = s; base < e; base += 64) {
        int idx = base + lane;
        int cc = 0; float cw = 0.f;
        if (idx < e) { cc = ws.csr_col[idx]; cw = ws.csr_w[idx]; }
        int n = min(64, e - base);
        for (int u = 0; u < n; ++u) {
          int   c2 = __shfl(cc, u);
          float w2 = __shfl(cw, u);
          acc += w2 * src[(size_t)c2 * 64 + lane];
        }
      }
      dst[(size_t)node * 64 + lane] = acc + dj * ws.h2[(size_t)node * 64 + lane];
    }
    g.sync();
  }

  // phase 8: log_softmax over buf0 -> out
  for (int node = wid0; node < NNODES; node += nwaves) {
    size_t idx = (size_t)node * 64 + lane;
    float v = ws.buf0[idx];
    float m = v;
#pragma unroll
    for (int o = 32; o > 0; o >>= 1) m = fmaxf(m, __shfl_xor(m, o));
    float s = __expf(v - m);
#pragma unroll
    for (int o = 32; o > 0; o >>= 1) s += __shfl_xor(s, o);
    out[idx] = (v - m) - __logf(s);
  }
}

// ---------------- host ----------------
extern "C" void kernel_launch(void* const* d_in, const int* in_sizes, int n_in,
                              void* d_out, int out_size, void* d_ws, size_t ws_size,
                              hipStream_t stream) {
  const float* x    = (const float*)d_in[0];
  const int*   ei   = (const int*)  d_in[1];
  const float* W1   = (const float*)d_in[2];
  const float* b1   = (const float*)d_in[3];
  const float* W2   = (const float*)d_in[4];
  const float* b2   = (const float*)d_in[5];
  const float* temp = (const float*)d_in[6];
  float* out = (float*)d_out;

  char* w = (char*)d_ws;
  size_t o = 0;
  auto bump = [&](size_t bytes) { size_t r = o; o += (bytes + 255) & ~(size_t)255; return r; };
  WS ws;
  ws.d       = (float*)(w + bump(11 * 4));
  ws.jmax    = (int*)  (w + bump(4));
  ws.cnt     = (int*)  (w + bump((size_t)NNODES * 4));
  ws.off     = (int*)  (w + bump((size_t)(NNODES + 1) * 4));
  ws.cursor  = (int*)  (w + bump((size_t)NNODES * 4));
  ws.dinv    = (float*)(w + bump((size_t)NNODES * 4));
  ws.csr_col = (int*)  (w + bump((size_t)NEDGES * 4));
  ws.csr_w   = (float*)(w + bump((size_t)NEDGES * 4));
  ws.h2      = (float*)(w + bump((size_t)NNODES * 64 * 4));
  ws.buf0    = (float*)(w + bump((size_t)NNODES * 64 * 4));
  ws.buf1    = (float*)(w + bump((size_t)NNODES * 64 * 4));
  ws.w1s     = (short*)(w + bump((size_t)512 * 256 * 2));
  ws.w2s     = (short*)(w + bump((size_t)256 * 64 * 2));
  ws.bsum    = (int*)  (w + bump(512 * 4));
  ws.bbase   = (int*)  (w + bump(512 * 4));

  const int MBLK = (NNODES + 63) / 64;  // 1563

  k_swzall<<<73, 256, 0, stream>>>(W1, W2, temp, ws);
  k_fwd<<<MBLK, 256, 0, stream>>>(x, b1, b2, ws, out);

  void* args[] = { (void*)&ei, (void*)&ws, (void*)&out };
  hipLaunchCooperativeKernel((void*)k_graph, dim3(512), dim3(256), args, 0, stream);
}